// Round 6
// baseline (26.033 us; speedup 1.0000x reference)
//
#include <hip/hip_runtime.h>
#include <math.h>

#define KTOT 4096
#define BNUM 64
#define MNUM 64
#define NITER 8
#define NBLK 192   // 64 batches x 3 combos

// packed lower-tri index (j<=i)
#define LIDX(i,j) ((i)*((i)+1)/2 + (j))

__device__ const float c_cls_mean[3][3] = {
    {1.76255119f, 0.66068622f, 0.84422524f},
    {1.52563191462f, 1.62856739989f, 3.88311640418f},
    {1.73698127f, 0.59706367f, 1.76282397f}
};

// symmetric-3x3 packed access: (0,0)=0 (0,1)=1 (0,2)=2 (1,1)=3 (1,2)=4 (2,2)=5
__device__ __forceinline__ double sym3(const double* a, int i, int j) {
    const int lo = i < j ? i : j, hi = i < j ? j : i;
    return a[lo == 0 ? hi : (lo == 1 ? hi + 2 : 5)];
}
// Full Gram accessor from the 24 unique entries.
// G = [[B, 0, U],[0, B, V],[U^T, V^T, D]]  (U,V stored WITH the minus sign)
__device__ __forceinline__ double Gat(const double* B, const double* U,
                                      const double* V, const double* D,
                                      int i, int j) {
    if (j < i) { const int t = i; i = j; j = t; }
    if (j < 3)  return sym3(B, i, j);
    if (j < 6)  return (i < 3) ? 0.0 : sym3(B, i - 3, j - 3);
    if (i < 3)  return sym3(U, i, j - 6);
    if (i < 6)  return sym3(V, i - 3, j - 6);
    return sym3(D, i - 6, j - 6);
}

// Compute the 5 Qpred (x,z) points for element k under combo c (f32, matches JAX).
__device__ __forceinline__ void compute_qpred(
    int k, int combo,
    const float* __restrict__ center, const int* __restrict__ cls_ids,
    const float* __restrict__ ry, const float* __restrict__ size3d,
    const float* __restrict__ off_gt, const float* __restrict__ dep_gt,
    const float* __restrict__ out_off, const float* __restrict__ out_dep,
    const float* __restrict__ calibs, const float* __restrict__ trans_inv,
    float* qx, float* qz)
{
    const int b = k >> 6;
    const float cx = center[2*k];
    const int cid = cls_ids[k];
    const float d1 = size3d[3*k+1] + c_cls_mean[cid][1];
    const float d2 = size3d[3*k+2] + c_cls_mean[cid][2];
    float sn, cs;
    sincosf(ry[k], &sn, &cs);

    const float* C = calibs + b*12;
    const float f  = C[0];
    const float cu = C[2];
    const float tx = C[3];
    const float t_x = -tx / f;

    const float* TI = trans_inv + b*6;
    const float s   = TI[0];
    const float t0x = TI[2];

    float ox, dep;
    if (combo == 0)      { ox = off_gt[2*k];  dep = out_dep[k]; }
    else if (combo == 1) { ox = out_off[2*k]; dep = dep_gt[k]; }
    else                 { ox = out_off[2*k]; dep = out_dep[k]; }

    const float uv4x = (cx + ox) * 4.0f;
    const float projx = s * uv4x + t0x;
    const float px = (projx - cu) * dep / f + t_x;
    const float Px = px;
    const float Pz = dep;

    const float r1t[4] = {0.5f, -0.5f, -0.5f, 0.5f};
    const float r2t[4] = {0.5f,  0.5f, -0.5f, -0.5f};
    qx[0] = Px; qz[0] = Pz;
    #pragma unroll
    for (int n = 0; n < 4; ++n) {
        const float sx = d2 * r2t[n];
        const float sz = d1 * r1t[n];
        qx[n+1] = Px + (cs*sx + sn*sz);
        qz[n+1] = Pz + (-sn*sx + cs*sz);
    }
}

__device__ __forceinline__ double sl1(double p, double t) {
    double d = p - t, ad = fabs(d);
    return ad < 1.0 ? 0.5*d*d : ad - 0.5;
}

// One block = one (batch, combo). Gram (24 unique) -> redundant per-lane
// Cholesky + inverse iteration -> per-lane masked loss -> partial write.
// Last finished block folds all partials into the final scalar.
__global__ __launch_bounds__(64, 1) void fused_kernel(
    const float* __restrict__ center, const int* __restrict__ cls_ids,
    const float* __restrict__ ry, const float* __restrict__ size3d,
    const float* __restrict__ Pgt, const float* __restrict__ Qgt,
    const float* __restrict__ off_gt, const float* __restrict__ dep_gt,
    const float* __restrict__ out_off, const float* __restrict__ out_dep,
    const float* __restrict__ calibs, const float* __restrict__ trans_inv,
    double* __restrict__ partials, int* __restrict__ counter,
    float* __restrict__ out)
{
    const int b = blockIdx.x, combo = blockIdx.y;
    const int m = threadIdx.x;
    const int k = (b << 6) + m;

    float qx[5], qz[5];
    compute_qpred(k, combo, center, cls_ids, ry, size3d,
                  off_gt, dep_gt, out_off, out_dep, calibs, trans_inv, qx, qz);

    // ---- Gram accumulation: 24 unique entries (B, U=-S_u, V=-S_v, D) ----
    double B[6], U[6], V[6], D[6];
    #pragma unroll
    for (int i = 0; i < 6; ++i) { B[i]=0.0; U[i]=0.0; V[i]=0.0; D[i]=0.0; }

    double Px[5], Py[5];
    #pragma unroll
    for (int p = 0; p < 5; ++p) {
        const double x = (double)Pgt[(k*5+p)*2 + 0];
        const double y = (double)Pgt[(k*5+p)*2 + 1];
        Px[p] = x; Py[p] = y;
        const double u = (double)qx[p];
        const double v = (double)qz[p];
        const double w[6] = {x*x, x*y, x, y*y, y, 1.0};  // P (x) P packed sym
        const double uv2 = u*u + v*v;
        #pragma unroll
        for (int i = 0; i < 6; ++i) {
            B[i] += w[i];
            U[i] -= w[i]*u;
            V[i] -= w[i]*v;
            D[i] += w[i]*uv2;
        }
    }

    // ---- butterfly reduce (all lanes get full unique-Gram): 24 x 6 shfl ----
    #pragma unroll
    for (int off = 32; off > 0; off >>= 1) {
        #pragma unroll
        for (int i = 0; i < 6; ++i) {
            B[i] += __shfl_xor(B[i], off);
            U[i] += __shfl_xor(U[i], off);
            V[i] += __shfl_xor(V[i], off);
            D[i] += __shfl_xor(D[i], off);
        }
    }

    // ---- ridge shift on the diagonal (eigenvectors unchanged) ----
    double gmax = fmax(fmax(B[0], B[3]), fmax(B[5], fmax(D[0], fmax(D[3], D[5]))));
    const double ridge = 1e-10 * gmax;
    B[0] += ridge; B[3] += ridge; B[5] += ridge;
    D[0] += ridge; D[3] += ridge; D[5] += ridge;

    // ---- Cholesky: G = L L^T (packed lower tri), linv = 1/diag(L) ----
    double L[45], linv[9];
    #pragma unroll
    for (int i = 0; i < 9; ++i) {
        #pragma unroll
        for (int j = 0; j <= i; ++j) {
            double s = Gat(B, U, V, D, j, i);
            #pragma unroll
            for (int t = 0; t < j; ++t) s -= L[LIDX(i,t)] * L[LIDX(j,t)];
            if (j < i) {
                L[LIDX(i,j)] = s * linv[j];
            } else {
                const double d = fmax(s, ridge * 1e-2);  // pivot guard
                const double r = sqrt(d);
                L[LIDX(i,i)] = r;
                linv[i] = 1.0 / r;
            }
        }
    }

    // ---- inverse iteration: x <- normalize((L L^T)^{-1} x) ----
    double x[9];
    #pragma unroll
    for (int j = 0; j < 9; ++j) x[j] = 1.0 + 0.0625 * j;

    #pragma unroll 1
    for (int it = 0; it < NITER; ++it) {
        double y[9];
        #pragma unroll
        for (int i = 0; i < 9; ++i) {
            double s = x[i];
            #pragma unroll
            for (int t = 0; t < i; ++t) s -= L[LIDX(i,t)] * y[t];
            y[i] = s * linv[i];
        }
        double z[9];
        #pragma unroll
        for (int ii = 8; ii >= 0; --ii) {
            double s = y[ii];
            #pragma unroll
            for (int t = 8; t > 0; --t)
                if (t > ii) s -= L[LIDX(t,ii)] * z[t];
            z[ii] = s * linv[ii];
        }
        double n = 0.0;
        #pragma unroll
        for (int j = 0; j < 9; ++j) n += z[j]*z[j];
        const double inv = 1.0 / sqrt(n);
        #pragma unroll
        for (int j = 0; j < 9; ++j) x[j] = z[j] * inv;
    }

    // ---- per-lane masked loss with in-register H = x ----
    double hs = 0.0, hc = 0.0, rs = 0.0, rc = 0.0;
    #pragma unroll
    for (int p = 0; p < 5; ++p) {
        const double px_ = Px[p], py_ = Py[p];
        const double gx = (double)Qgt[(k*5+p)*3 + 0];
        const double gz = (double)Qgt[(k*5+p)*3 + 2];
        const double nw0 = x[0]*px_ + x[1]*py_ + x[2];
        const double nw1 = x[3]*px_ + x[4]*py_ + x[5];
        const double nw2 = x[6]*px_ + x[7]*py_ + x[8];
        const double den = nw2 + 1e-10;
        const double rx = nw0 / den;
        const double rz = nw1 / den;
        const bool msk = (rx > -40.0) && (rx < 40.0) && (rz > 0.0) && (rz < 80.0);
        if (msk) { hs += sl1(rx, gx) + sl1(rz, gz); hc += 2.0; }
        else     { rs += sl1((double)qx[p], gx) + sl1((double)qz[p], gz); rc += 2.0; }
    }

    #pragma unroll
    for (int off = 32; off > 0; off >>= 1) {
        hs += __shfl_xor(hs, off);
        hc += __shfl_xor(hc, off);
        rs += __shfl_xor(rs, off);
        rc += __shfl_xor(rc, off);
    }
    if (m == 0) {
        double* dst = partials + (size_t)(combo*BNUM + b) * 4;
        dst[0] = hs; dst[1] = hc; dst[2] = rs; dst[3] = rc;
    }

    // ---- last-block finalize (device-scope fence + atomic counter) ----
    __threadfence();                       // release: partial visible device-wide
    int last = 0;
    if (m == 0) last = (atomicAdd(counter, 1) == NBLK - 1);
    last = __shfl(last, 0);
    if (last) {
        __threadfence();                   // acquire: see all partials
        double acc[3][4];
        #pragma unroll
        for (int c = 0; c < 3; ++c)
            #pragma unroll
            for (int j = 0; j < 4; ++j)
                acc[c][j] = partials[(size_t)(c*BNUM + m) * 4 + j];
        #pragma unroll
        for (int off = 32; off > 0; off >>= 1) {
            #pragma unroll
            for (int c = 0; c < 3; ++c)
                #pragma unroll
                for (int j = 0; j < 4; ++j)
                    acc[c][j] += __shfl_xor(acc[c][j], off);
        }
        if (m == 0) {
            double tot = 0.0;
            #pragma unroll
            for (int c = 0; c < 3; ++c)
                tot += acc[c][0] / fmax(acc[c][1], 1.0)
                     + 0.5 * (acc[c][2] / fmax(acc[c][3], 1.0));
            out[0] = (float)(tot / 3.0);
        }
    }
}

extern "C" void kernel_launch(void* const* d_in, const int* in_sizes, int n_in,
                              void* d_out, int out_size, void* d_ws, size_t ws_size,
                              hipStream_t stream)
{
    const float* center  = (const float*)d_in[1];
    const int*   cls     = (const int*)  d_in[2];
    const float* ry      = (const float*)d_in[3];
    const float* size3d  = (const float*)d_in[4];
    const float* Pgt     = (const float*)d_in[5];
    const float* Qgt     = (const float*)d_in[6];
    const float* off_gt  = (const float*)d_in[7];
    const float* dep_gt  = (const float*)d_in[8];
    const float* out_off = (const float*)d_in[9];
    const float* out_dep = (const float*)d_in[10];
    const float* calibs  = (const float*)d_in[11];
    const float* tinv    = (const float*)d_in[12];

    double* partials = (double*)d_ws;                    // 192*4 doubles = 6144 B
    int*    counter  = (int*)((char*)d_ws + NBLK*4*sizeof(double));
    float*  out      = (float*)d_out;

    hipMemsetAsync(counter, 0, sizeof(int), stream);     // deterministic arrival count
    fused_kernel<<<dim3(BNUM,3), 64, 0, stream>>>(center, cls, ry, size3d, Pgt, Qgt,
        off_gt, dep_gt, out_off, out_dep, calibs, tinv, partials, counter, out);
}

// Round 7
// 15.070 us; speedup vs baseline: 1.7275x; 1.7275x over previous
//
#include <hip/hip_runtime.h>
#include <math.h>

#define KTOT 4096
#define BNUM 64
#define MNUM 64
#define NITER 8

// packed lower-tri index (j<=i)
#define LIDX(i,j) ((i)*((i)+1)/2 + (j))

__device__ const float c_cls_mean[3][3] = {
    {1.76255119f, 0.66068622f, 0.84422524f},
    {1.52563191462f, 1.62856739989f, 3.88311640418f},
    {1.73698127f, 0.59706367f, 1.76282397f}
};

// symmetric-3x3 packed access: (0,0)=0 (0,1)=1 (0,2)=2 (1,1)=3 (1,2)=4 (2,2)=5
__device__ __forceinline__ double sym3(const double* a, int i, int j) {
    const int lo = i < j ? i : j, hi = i < j ? j : i;
    return a[lo == 0 ? hi : (lo == 1 ? hi + 2 : 5)];
}
// Full Gram accessor from the 24 unique entries.
// G = [[B, 0, U],[0, B, V],[U^T, V^T, D]]  (U,V stored WITH the minus sign)
__device__ __forceinline__ double Gat(const double* B, const double* U,
                                      const double* V, const double* D,
                                      int i, int j) {
    if (j < i) { const int t = i; i = j; j = t; }
    if (j < 3)  return sym3(B, i, j);
    if (j < 6)  return (i < 3) ? 0.0 : sym3(B, i - 3, j - 3);
    if (i < 3)  return sym3(U, i, j - 6);
    if (i < 6)  return sym3(V, i - 3, j - 6);
    return sym3(D, i - 6, j - 6);
}

// Compute the 5 Qpred (x,z) points for element k under combo c (f32, matches JAX).
__device__ __forceinline__ void compute_qpred(
    int k, int combo,
    const float* __restrict__ center, const int* __restrict__ cls_ids,
    const float* __restrict__ ry, const float* __restrict__ size3d,
    const float* __restrict__ off_gt, const float* __restrict__ dep_gt,
    const float* __restrict__ out_off, const float* __restrict__ out_dep,
    const float* __restrict__ calibs, const float* __restrict__ trans_inv,
    float* qx, float* qz)
{
    const int b = k >> 6;
    const float cx = center[2*k];
    const int cid = cls_ids[k];
    const float d1 = size3d[3*k+1] + c_cls_mean[cid][1];
    const float d2 = size3d[3*k+2] + c_cls_mean[cid][2];
    float sn, cs;
    sincosf(ry[k], &sn, &cs);

    const float* C = calibs + b*12;
    const float f  = C[0];
    const float cu = C[2];
    const float tx = C[3];
    const float t_x = -tx / f;

    const float* TI = trans_inv + b*6;
    const float s   = TI[0];
    const float t0x = TI[2];

    float ox, dep;
    if (combo == 0)      { ox = off_gt[2*k];  dep = out_dep[k]; }
    else if (combo == 1) { ox = out_off[2*k]; dep = dep_gt[k]; }
    else                 { ox = out_off[2*k]; dep = out_dep[k]; }

    const float uv4x = (cx + ox) * 4.0f;
    const float projx = s * uv4x + t0x;
    const float px = (projx - cu) * dep / f + t_x;
    const float Px = px;
    const float Pz = dep;

    const float r1t[4] = {0.5f, -0.5f, -0.5f, 0.5f};
    const float r2t[4] = {0.5f,  0.5f, -0.5f, -0.5f};
    qx[0] = Px; qz[0] = Pz;
    #pragma unroll
    for (int n = 0; n < 4; ++n) {
        const float sx = d2 * r2t[n];
        const float sz = d1 * r1t[n];
        qx[n+1] = Px + (cs*sx + sn*sz);
        qz[n+1] = Pz + (-sn*sx + cs*sz);
    }
}

__device__ __forceinline__ double sl1(double p, double t) {
    double d = p - t, ad = fabs(d);
    return ad < 1.0 ? 0.5*d*d : ad - 0.5;
}

// One block = one (batch, combo). Gram (24 unique) -> redundant per-lane
// Cholesky + inverse iteration -> per-lane masked loss -> one partial write.
__global__ __launch_bounds__(64, 1) void fused_kernel(
    const float* __restrict__ center, const int* __restrict__ cls_ids,
    const float* __restrict__ ry, const float* __restrict__ size3d,
    const float* __restrict__ Pgt, const float* __restrict__ Qgt,
    const float* __restrict__ off_gt, const float* __restrict__ dep_gt,
    const float* __restrict__ out_off, const float* __restrict__ out_dep,
    const float* __restrict__ calibs, const float* __restrict__ trans_inv,
    double* __restrict__ partials)
{
    const int b = blockIdx.x, combo = blockIdx.y;
    const int m = threadIdx.x;
    const int k = (b << 6) + m;

    float qx[5], qz[5];
    compute_qpred(k, combo, center, cls_ids, ry, size3d,
                  off_gt, dep_gt, out_off, out_dep, calibs, trans_inv, qx, qz);

    // ---- Gram accumulation: 24 unique entries (B, U=-S_u, V=-S_v, D) ----
    double B[6], U[6], V[6], D[6];
    #pragma unroll
    for (int i = 0; i < 6; ++i) { B[i]=0.0; U[i]=0.0; V[i]=0.0; D[i]=0.0; }

    double Px[5], Py[5];
    #pragma unroll
    for (int p = 0; p < 5; ++p) {
        const double x = (double)Pgt[(k*5+p)*2 + 0];
        const double y = (double)Pgt[(k*5+p)*2 + 1];
        Px[p] = x; Py[p] = y;
        const double u = (double)qx[p];
        const double v = (double)qz[p];
        const double w[6] = {x*x, x*y, x, y*y, y, 1.0};  // P (x) P packed sym
        const double uv2 = u*u + v*v;
        #pragma unroll
        for (int i = 0; i < 6; ++i) {
            B[i] += w[i];
            U[i] -= w[i]*u;
            V[i] -= w[i]*v;
            D[i] += w[i]*uv2;
        }
    }

    // ---- butterfly reduce (all lanes get full unique-Gram): 24 x 6 shfl ----
    #pragma unroll
    for (int off = 32; off > 0; off >>= 1) {
        #pragma unroll
        for (int i = 0; i < 6; ++i) {
            B[i] += __shfl_xor(B[i], off);
            U[i] += __shfl_xor(U[i], off);
            V[i] += __shfl_xor(V[i], off);
            D[i] += __shfl_xor(D[i], off);
        }
    }

    // ---- ridge shift on the diagonal (eigenvectors unchanged) ----
    double gmax = fmax(fmax(B[0], B[3]), fmax(B[5], fmax(D[0], fmax(D[3], D[5]))));
    const double ridge = 1e-10 * gmax;
    B[0] += ridge; B[3] += ridge; B[5] += ridge;
    D[0] += ridge; D[3] += ridge; D[5] += ridge;

    // ---- Cholesky: G = L L^T (packed lower tri), linv = 1/diag(L) ----
    double L[45], linv[9];
    #pragma unroll
    for (int i = 0; i < 9; ++i) {
        #pragma unroll
        for (int j = 0; j <= i; ++j) {
            double s = Gat(B, U, V, D, j, i);
            #pragma unroll
            for (int t = 0; t < j; ++t) s -= L[LIDX(i,t)] * L[LIDX(j,t)];
            if (j < i) {
                L[LIDX(i,j)] = s * linv[j];
            } else {
                const double d = fmax(s, ridge * 1e-2);  // pivot guard
                const double r = sqrt(d);
                L[LIDX(i,i)] = r;
                linv[i] = 1.0 / r;
            }
        }
    }

    // ---- inverse iteration, UNNORMALIZED (f64 range >> shrink factor);
    //      single normalization at the end ----
    double x[9];
    #pragma unroll
    for (int j = 0; j < 9; ++j) x[j] = 1.0 + 0.0625 * j;

    #pragma unroll 1
    for (int it = 0; it < NITER; ++it) {
        double y[9];
        #pragma unroll
        for (int i = 0; i < 9; ++i) {
            double s = x[i];
            #pragma unroll
            for (int t = 0; t < i; ++t) s -= L[LIDX(i,t)] * y[t];
            y[i] = s * linv[i];
        }
        #pragma unroll
        for (int ii = 8; ii >= 0; --ii) {
            double s = y[ii];
            #pragma unroll
            for (int t = 8; t > 0; --t)
                if (t > ii) s -= L[LIDX(t,ii)] * x[t];
            x[ii] = s * linv[ii];
        }
    }
    {
        double n = 0.0;
        #pragma unroll
        for (int j = 0; j < 9; ++j) n += x[j]*x[j];
        const double inv = 1.0 / sqrt(n);
        #pragma unroll
        for (int j = 0; j < 9; ++j) x[j] *= inv;
    }

    // ---- per-lane masked loss with in-register H = x ----
    double hs = 0.0, hc = 0.0, rs = 0.0, rc = 0.0;
    #pragma unroll
    for (int p = 0; p < 5; ++p) {
        const double px_ = Px[p], py_ = Py[p];
        const double gx = (double)Qgt[(k*5+p)*3 + 0];
        const double gz = (double)Qgt[(k*5+p)*3 + 2];
        const double nw0 = x[0]*px_ + x[1]*py_ + x[2];
        const double nw1 = x[3]*px_ + x[4]*py_ + x[5];
        const double nw2 = x[6]*px_ + x[7]*py_ + x[8];
        const double den = nw2 + 1e-10;
        const double rx = nw0 / den;
        const double rz = nw1 / den;
        const bool msk = (rx > -40.0) && (rx < 40.0) && (rz > 0.0) && (rz < 80.0);
        if (msk) { hs += sl1(rx, gx) + sl1(rz, gz); hc += 2.0; }
        else     { rs += sl1((double)qx[p], gx) + sl1((double)qz[p], gz); rc += 2.0; }
    }

    #pragma unroll
    for (int off = 32; off > 0; off >>= 1) {
        hs += __shfl_xor(hs, off);
        hc += __shfl_xor(hc, off);
        rs += __shfl_xor(rs, off);
        rc += __shfl_xor(rc, off);
    }
    if (m == 0) {
        double* dst = partials + (size_t)(combo*BNUM + b) * 4;
        dst[0] = hs; dst[1] = hc; dst[2] = rs; dst[3] = rc;
    }
}

// Single wave: fold 192x4 partials -> final scalar.
__global__ __launch_bounds__(64) void finalize2(
    const double* __restrict__ partials, float* __restrict__ out)
{
    const int t = threadIdx.x;
    double acc[3][4];
    #pragma unroll
    for (int c = 0; c < 3; ++c)
        #pragma unroll
        for (int j = 0; j < 4; ++j)
            acc[c][j] = partials[(size_t)(c*BNUM + t) * 4 + j];

    #pragma unroll
    for (int off = 32; off > 0; off >>= 1) {
        #pragma unroll
        for (int c = 0; c < 3; ++c)
            #pragma unroll
            for (int j = 0; j < 4; ++j)
                acc[c][j] += __shfl_xor(acc[c][j], off);
    }
    if (t == 0) {
        double tot = 0.0;
        #pragma unroll
        for (int c = 0; c < 3; ++c)
            tot += acc[c][0] / fmax(acc[c][1], 1.0)
                 + 0.5 * (acc[c][2] / fmax(acc[c][3], 1.0));
        out[0] = (float)(tot / 3.0);
    }
}

extern "C" void kernel_launch(void* const* d_in, const int* in_sizes, int n_in,
                              void* d_out, int out_size, void* d_ws, size_t ws_size,
                              hipStream_t stream)
{
    const float* center  = (const float*)d_in[1];
    const int*   cls     = (const int*)  d_in[2];
    const float* ry      = (const float*)d_in[3];
    const float* size3d  = (const float*)d_in[4];
    const float* Pgt     = (const float*)d_in[5];
    const float* Qgt     = (const float*)d_in[6];
    const float* off_gt  = (const float*)d_in[7];
    const float* dep_gt  = (const float*)d_in[8];
    const float* out_off = (const float*)d_in[9];
    const float* out_dep = (const float*)d_in[10];
    const float* calibs  = (const float*)d_in[11];
    const float* tinv    = (const float*)d_in[12];

    double* partials = (double*)d_ws;   // 192*4 doubles
    float*  out      = (float*)d_out;

    fused_kernel<<<dim3(BNUM,3), 64, 0, stream>>>(center, cls, ry, size3d, Pgt, Qgt,
        off_gt, dep_gt, out_off, out_dep, calibs, tinv, partials);
    finalize2<<<1, 64, 0, stream>>>(partials, out);
}

// Round 8
// 13.236 us; speedup vs baseline: 1.9669x; 1.1386x over previous
//
#include <hip/hip_runtime.h>
#include <math.h>

#define KTOT 4096
#define BNUM 64
#define MNUM 64
#define NITER 5

// packed lower-tri index (j<=i)
#define LIDX(i,j) ((i)*((i)+1)/2 + (j))

__device__ const float c_cls_mean[3][3] = {
    {1.76255119f, 0.66068622f, 0.84422524f},
    {1.52563191462f, 1.62856739989f, 3.88311640418f},
    {1.73698127f, 0.59706367f, 1.76282397f}
};

// symmetric-3x3 packed access: (0,0)=0 (0,1)=1 (0,2)=2 (1,1)=3 (1,2)=4 (2,2)=5
__device__ __forceinline__ double sym3(const double* a, int i, int j) {
    const int lo = i < j ? i : j, hi = i < j ? j : i;
    return a[lo == 0 ? hi : (lo == 1 ? hi + 2 : 5)];
}
// Full Gram accessor from the 24 unique entries.
// G = [[B, 0, U],[0, B, V],[U^T, V^T, D]]  (U,V stored WITH the minus sign)
__device__ __forceinline__ double Gat(const double* B, const double* U,
                                      const double* V, const double* D,
                                      int i, int j) {
    if (j < i) { const int t = i; i = j; j = t; }
    if (j < 3)  return sym3(B, i, j);
    if (j < 6)  return (i < 3) ? 0.0 : sym3(B, i - 3, j - 3);
    if (i < 3)  return sym3(U, i, j - 6);
    if (i < 6)  return sym3(V, i - 3, j - 6);
    return sym3(D, i - 6, j - 6);
}

// Compute the 5 Qpred (x,z) points for element k under combo c (f32, matches JAX).
__device__ __forceinline__ void compute_qpred(
    int k, int combo,
    const float* __restrict__ center, const int* __restrict__ cls_ids,
    const float* __restrict__ ry, const float* __restrict__ size3d,
    const float* __restrict__ off_gt, const float* __restrict__ dep_gt,
    const float* __restrict__ out_off, const float* __restrict__ out_dep,
    const float* __restrict__ calibs, const float* __restrict__ trans_inv,
    float* qx, float* qz)
{
    const int b = k >> 6;
    const float cx = center[2*k];
    const int cid = cls_ids[k];
    const float d1 = size3d[3*k+1] + c_cls_mean[cid][1];
    const float d2 = size3d[3*k+2] + c_cls_mean[cid][2];
    float sn, cs;
    sincosf(ry[k], &sn, &cs);

    const float* C = calibs + b*12;
    const float f  = C[0];
    const float cu = C[2];
    const float tx = C[3];
    const float t_x = -tx / f;

    const float* TI = trans_inv + b*6;
    const float s   = TI[0];
    const float t0x = TI[2];

    float ox, dep;
    if (combo == 0)      { ox = off_gt[2*k];  dep = out_dep[k]; }
    else if (combo == 1) { ox = out_off[2*k]; dep = dep_gt[k]; }
    else                 { ox = out_off[2*k]; dep = out_dep[k]; }

    const float uv4x = (cx + ox) * 4.0f;
    const float projx = s * uv4x + t0x;
    const float px = (projx - cu) * dep / f + t_x;
    const float Px = px;
    const float Pz = dep;

    const float r1t[4] = {0.5f, -0.5f, -0.5f, 0.5f};
    const float r2t[4] = {0.5f,  0.5f, -0.5f, -0.5f};
    qx[0] = Px; qz[0] = Pz;
    #pragma unroll
    for (int n = 0; n < 4; ++n) {
        const float sx = d2 * r2t[n];
        const float sz = d1 * r1t[n];
        qx[n+1] = Px + (cs*sx + sn*sz);
        qz[n+1] = Pz + (-sn*sx + cs*sz);
    }
}

__device__ __forceinline__ double sl1(double p, double t) {
    double d = p - t, ad = fabs(d);
    return ad < 1.0 ? 0.5*d*d : ad - 0.5;
}

// One block = one (batch, combo). Gram (24 unique) -> redundant per-lane
// LDL^T factorization + inverse iteration -> per-lane masked loss -> partial write.
__global__ __launch_bounds__(64, 1) void fused_kernel(
    const float* __restrict__ center, const int* __restrict__ cls_ids,
    const float* __restrict__ ry, const float* __restrict__ size3d,
    const float* __restrict__ Pgt, const float* __restrict__ Qgt,
    const float* __restrict__ off_gt, const float* __restrict__ dep_gt,
    const float* __restrict__ out_off, const float* __restrict__ out_dep,
    const float* __restrict__ calibs, const float* __restrict__ trans_inv,
    double* __restrict__ partials)
{
    const int b = blockIdx.x, combo = blockIdx.y;
    const int m = threadIdx.x;
    const int k = (b << 6) + m;

    float qx[5], qz[5];
    compute_qpred(k, combo, center, cls_ids, ry, size3d,
                  off_gt, dep_gt, out_off, out_dep, calibs, trans_inv, qx, qz);

    // ---- Gram accumulation: 24 unique entries (B, U=-S_u, V=-S_v, D) ----
    double B[6], U[6], V[6], D[6];
    #pragma unroll
    for (int i = 0; i < 6; ++i) { B[i]=0.0; U[i]=0.0; V[i]=0.0; D[i]=0.0; }

    double Px[5], Py[5];
    #pragma unroll
    for (int p = 0; p < 5; ++p) {
        const float2 P2 = *reinterpret_cast<const float2*>(&Pgt[(k*5+p)*2]);
        const double x = (double)P2.x;
        const double y = (double)P2.y;
        Px[p] = x; Py[p] = y;
        const double u = (double)qx[p];
        const double v = (double)qz[p];
        const double w[6] = {x*x, x*y, x, y*y, y, 1.0};  // P (x) P packed sym
        const double uv2 = u*u + v*v;
        #pragma unroll
        for (int i = 0; i < 6; ++i) {
            B[i] += w[i];
            U[i] -= w[i]*u;
            V[i] -= w[i]*v;
            D[i] += w[i]*uv2;
        }
    }

    // ---- butterfly reduce (all lanes get full unique-Gram): 24 x 6 shfl ----
    #pragma unroll
    for (int off = 32; off > 0; off >>= 1) {
        #pragma unroll
        for (int i = 0; i < 6; ++i) {
            B[i] += __shfl_xor(B[i], off);
            U[i] += __shfl_xor(U[i], off);
            V[i] += __shfl_xor(V[i], off);
            D[i] += __shfl_xor(D[i], off);
        }
    }

    // ---- ridge shift on the diagonal (eigenvectors unchanged) ----
    double gmax = fmax(fmax(B[0], B[3]), fmax(B[5], fmax(D[0], fmax(D[3], D[5]))));
    const double ridge = 1e-10 * gmax;
    B[0] += ridge; B[3] += ridge; B[5] += ridge;
    D[0] += ridge; D[3] += ridge; D[5] += ridge;

    // ---- LDL^T: G = L D L^T, L unit-lower (off-diag packed), Dinv = 1/D ----
    // No f64 sqrt anywhere in the factorization chain.
    double Lf[45], Dinv[9];
    #pragma unroll
    for (int i = 0; i < 9; ++i) {
        double w[9];                 // w[t] = L_it * D_t for this row (== pre-division s)
        double diag = Gat(B, U, V, D, i, i);
        #pragma unroll
        for (int j = 0; j < 9; ++j) {
            if (j < i) {
                double s = Gat(B, U, V, D, j, i);
                #pragma unroll
                for (int t = 0; t < 9; ++t)
                    if (t < j) s -= Lf[LIDX(j,t)] * w[t];
                const double lij = s * Dinv[j];
                Lf[LIDX(i,j)] = lij;
                w[j] = s;
                diag -= lij * s;
            }
        }
        Dinv[i] = 1.0 / fmax(diag, ridge * 1e-2);   // pivot guard
    }

    // ---- inverse iteration, UNNORMALIZED; single normalization at end ----
    double x[9];
    #pragma unroll
    for (int j = 0; j < 9; ++j) x[j] = 1.0 + 0.0625 * j;

    #pragma unroll 1
    for (int it = 0; it < NITER; ++it) {
        double y[9];
        #pragma unroll
        for (int i = 0; i < 9; ++i) {          // fwd: unit lower
            double s = x[i];
            #pragma unroll
            for (int t = 0; t < 9; ++t)
                if (t < i) s -= Lf[LIDX(i,t)] * y[t];
            y[i] = s;
        }
        #pragma unroll
        for (int i = 8; i >= 0; --i) {         // diag + bwd: unit upper
            double s = y[i] * Dinv[i];
            #pragma unroll
            for (int t = 8; t > 0; --t)
                if (t > i) s -= Lf[LIDX(t,i)] * x[t];
            x[i] = s;                           // overwrite x with new iterate
        }
    }
    {
        double n = 0.0;
        #pragma unroll
        for (int j = 0; j < 9; ++j) n += x[j]*x[j];
        const double inv = 1.0 / sqrt(n);
        #pragma unroll
        for (int j = 0; j < 9; ++j) x[j] *= inv;
    }

    // ---- per-lane masked loss with in-register H = x ----
    double hs = 0.0, hc = 0.0, rs = 0.0;
    #pragma unroll
    for (int p = 0; p < 5; ++p) {
        const double px_ = Px[p], py_ = Py[p];
        const double gx = (double)Qgt[(k*5+p)*3 + 0];
        const double gz = (double)Qgt[(k*5+p)*3 + 2];
        const double nw0 = x[0]*px_ + x[1]*py_ + x[2];
        const double nw1 = x[3]*px_ + x[4]*py_ + x[5];
        const double nw2 = x[6]*px_ + x[7]*py_ + x[8];
        const double inv = 1.0 / (nw2 + 1e-10);
        const double rx = nw0 * inv;
        const double rz = nw1 * inv;
        const bool msk = (rx > -40.0) && (rx < 40.0) && (rz > 0.0) && (rz < 80.0);
        if (msk) { hs += sl1(rx, gx) + sl1(rz, gz); hc += 2.0; }
        else     { rs += sl1((double)qx[p], gx) + sl1((double)qz[p], gz); }
    }

    #pragma unroll
    for (int off = 32; off > 0; off >>= 1) {
        hs += __shfl_xor(hs, off);
        hc += __shfl_xor(hc, off);
        rs += __shfl_xor(rs, off);
    }
    if (m == 0) {
        double* dst = partials + (size_t)(combo*BNUM + b) * 3;
        dst[0] = hs; dst[1] = hc; dst[2] = rs;
    }
}

// Single wave: fold 192x3 partials -> final scalar.
// Per block hc+rc = 64 lanes * 10 = 640; per combo HC+RC = 64*640 = 40960.
__global__ __launch_bounds__(64) void finalize2(
    const double* __restrict__ partials, float* __restrict__ out)
{
    const int t = threadIdx.x;
    double acc[3][3];
    #pragma unroll
    for (int c = 0; c < 3; ++c)
        #pragma unroll
        for (int j = 0; j < 3; ++j)
            acc[c][j] = partials[(size_t)(c*BNUM + t) * 3 + j];

    #pragma unroll
    for (int off = 32; off > 0; off >>= 1) {
        #pragma unroll
        for (int c = 0; c < 3; ++c)
            #pragma unroll
            for (int j = 0; j < 3; ++j)
                acc[c][j] += __shfl_xor(acc[c][j], off);
    }
    if (t == 0) {
        double tot = 0.0;
        #pragma unroll
        for (int c = 0; c < 3; ++c) {
            const double hc = acc[c][1];
            const double rc = 40960.0 - hc;
            tot += acc[c][0] / fmax(hc, 1.0)
                 + 0.5 * (acc[c][2] / fmax(rc, 1.0));
        }
        out[0] = (float)(tot / 3.0);
    }
}

extern "C" void kernel_launch(void* const* d_in, const int* in_sizes, int n_in,
                              void* d_out, int out_size, void* d_ws, size_t ws_size,
                              hipStream_t stream)
{
    const float* center  = (const float*)d_in[1];
    const int*   cls     = (const int*)  d_in[2];
    const float* ry      = (const float*)d_in[3];
    const float* size3d  = (const float*)d_in[4];
    const float* Pgt     = (const float*)d_in[5];
    const float* Qgt     = (const float*)d_in[6];
    const float* off_gt  = (const float*)d_in[7];
    const float* dep_gt  = (const float*)d_in[8];
    const float* out_off = (const float*)d_in[9];
    const float* out_dep = (const float*)d_in[10];
    const float* calibs  = (const float*)d_in[11];
    const float* tinv    = (const float*)d_in[12];

    double* partials = (double*)d_ws;   // 192*3 doubles
    float*  out      = (float*)d_out;

    fused_kernel<<<dim3(BNUM,3), 64, 0, stream>>>(center, cls, ry, size3d, Pgt, Qgt,
        off_gt, dep_gt, out_off, out_dep, calibs, tinv, partials);
    finalize2<<<1, 64, 0, stream>>>(partials, out);
}